// Round 10
// baseline (363.013 us; speedup 1.0000x reference)
//
#include <hip/hip_runtime.h>
#include <hip/hip_bf16.h>

#define DEV __device__ __forceinline__

typedef __attribute__((ext_vector_type(8))) short bf16x8;
typedef __attribute__((ext_vector_type(8))) unsigned short u16x8;
typedef __attribute__((ext_vector_type(4))) float f32x4;

union U4B8 { uint4 u; bf16x8 b; };

DEV float bf2f(__hip_bfloat16 v) { return __bfloat162float(v); }
DEV float us2f(unsigned short u) { return __uint_as_float(((unsigned)u) << 16); }
DEV float lrelu(float x) { return x > 0.f ? x : 0.2f * x; }
DEV float eluf(float x) { return x > 0.f ? x : (__expf(x) - 1.f); }

// fp32 -> bf16 bits, round-to-nearest-even
DEV unsigned short f2bf(float x) {
    unsigned int u = __float_as_uint(x);
    return (unsigned short)((u + 0x7FFFu + ((u >> 16) & 1u)) >> 16);
}

// Read element i of a float tensor that is either bf16 (f=1) or fp32 (f=0).
DEV float ldf(const void* p, int i, int f) {
    return f ? bf2f(((const __hip_bfloat16*)p)[i]) : ((const float*)p)[i];
}

// Inline dtype detection: bf16 low-half exponent test, 64 samples.
// Only call on arrays >= 256B (64 u32 samples).
DEV int detect_bf16(const void* p) {
    const unsigned int* w = (const unsigned int*)p;
    unsigned int e = (w[threadIdx.x & 63] >> 7) & 0xFFu;
    int hit = (e >= 112u && e <= 130u) ? 1 : 0;
    unsigned long long b = __ballot(hit);
    return __popcll(b) > 32 ? 1 : 0;
}

// Load 8 consecutive "float" elems as 8 packed bf16 (16B).
// mode==0: src is our own bf16 buffer. mode==1: raw input, branch on f.
DEV uint4 ld8(const void* src, size_t off, int mode, int f) {
    if (mode == 0 || f) return *(const uint4*)((const unsigned short*)src + off);
    const float* s = (const float*)src + off;
    float4 a = *(const float4*)s, b = *(const float4*)(s + 4);
    uint4 r;
    r.x = f2bf(a.x) | ((unsigned)f2bf(a.y) << 16);
    r.y = f2bf(a.z) | ((unsigned)f2bf(a.w) << 16);
    r.z = f2bf(b.x) | ((unsigned)f2bf(b.y) << 16);
    r.w = f2bf(b.z) | ((unsigned)f2bf(b.w) << 16);
    return r;
}

// ---------------- P buffer: biases + BN params only (weights read raw) ----------------

struct Ptrs6 { const void* p[6]; };  // b0,b1,b2,gamma,beta,[5]=x1 for detect

#define P_B0 0
#define P_B1 64
#define P_B2 128
#define P_GAMMA 144
#define P_BETA 160
#define P_TOTAL 176

DEV void params_dev(Ptrs6 pp, float* __restrict__ P) {
    const int narr[5] = {64, 64, 16, 16, 16};
    const int oarr[5] = {P_B0, P_B1, P_B2, P_GAMMA, P_BETA};
    int f = detect_bf16(pp.p[5]);
    for (int a = 0; a < 5; a++)
        for (int i = threadIdx.x; i < narr[a]; i += 256)
            P[oarr[a] + i] = ldf(pp.p[a], i, f);
}

// ---------------- CSR build: contention-free 3-phase bucket sort ----------------
// Buckets are 512 nodes (SH=9). bedge entry packed: (src << 9) | (dst & 511).
// Valid while N < 2^23. k_place reorders its chunk through LDS so bedge
// writes go out as per-bucket contiguous runs instead of scattered 4B stores.
// NBLK=1024: halved chunk halves the serial chain, ~29KB LDS fits ~5 blk/CU.

#define SH 9
#define BK 512
#define CAPB 12288
#define NBLK 1024
#define NBMX 512
#define CHUNK_MAX 3328

DEV void count_dev(int blk, const int* __restrict__ ei1, const int* __restrict__ ei2,
                   int E, int* __restrict__ counts, int nb, int NB, int chunk)
{
    __shared__ int lcnt[NBMX];
    int t = threadIdx.x;
    for (int b = t; b < NB; b += 256) lcnt[b] = 0;
    __syncthreads();
    int i0 = blk * chunk, i1 = min(i0 + chunk, 2 * E);
    for (int i = i0 + t; i < i1; i += 256) {
        int b;
        if (i < E) b = ei1[E + i] >> SH;
        else       b = (ei2[i] >> SH) + nb;
        atomicAdd(&lcnt[b], 1);
    }
    __syncthreads();
    for (int b = t; b < NB; b += 256) counts[b * NBLK + blk] = lcnt[b];
}

__global__ __launch_bounds__(256) void k_scan(
    int* __restrict__ counts, int* __restrict__ bfill)
{
    int b = blockIdx.x, t = threadIdx.x;
    __shared__ int ps[256];
    int* row = counts + b * NBLK;
    int x0 = row[4 * t], x1 = row[4 * t + 1], x2 = row[4 * t + 2], x3 = row[4 * t + 3];
    int sum = x0 + x1 + x2 + x3;
    ps[t] = sum;
    __syncthreads();
    #pragma unroll
    for (int off = 1; off < 256; off <<= 1) {
        int v = (t >= off) ? ps[t - off] : 0;
        __syncthreads();
        ps[t] += v;
        __syncthreads();
    }
    int excl = ps[t] - sum;
    row[4 * t]     = excl;
    row[4 * t + 1] = excl + x0;
    row[4 * t + 2] = excl + x0 + x1;
    row[4 * t + 3] = excl + x0 + x1 + x2;
    if (t == 255) bfill[b] = ps[255];
}

__global__ __launch_bounds__(256) void k_place(
    const int* __restrict__ ei1, const int* __restrict__ ei2, int E,
    const int* __restrict__ counts, unsigned int* __restrict__ bedge,
    int nb, int NB, int chunk)
{
    __shared__ unsigned int payload[CHUNK_MAX];
    __shared__ unsigned short lbuck[CHUNK_MAX];
    __shared__ int lcnt[NBMX], lofs[NBMX], lpos[NBMX], pofs[NBMX];
    __shared__ int ps[256];
    int t = threadIdx.x, blk = blockIdx.x;
    int i0 = blk * chunk, i1 = min(i0 + chunk, 2 * E);

    if (chunk <= CHUNK_MAX && NB <= NBMX) {
        for (int b = t; b < NBMX; b += 256) { lcnt[b] = 0; lpos[b] = 0; }
        __syncthreads();
        for (int i = i0 + t; i < i1; i += 256) {
            int b;
            if (i < E) b = ei1[E + i] >> SH;
            else       b = (ei2[i] >> SH) + nb;
            atomicAdd(&lcnt[b], 1);
        }
        __syncthreads();
        int a0 = lcnt[2 * t], a1 = lcnt[2 * t + 1];
        ps[t] = a0 + a1;
        __syncthreads();
        #pragma unroll
        for (int off = 1; off < 256; off <<= 1) {
            int v = (t >= off) ? ps[t - off] : 0;
            __syncthreads();
            ps[t] += v;
            __syncthreads();
        }
        int excl = ps[t] - (a0 + a1);
        lofs[2 * t] = excl;
        lofs[2 * t + 1] = excl + a0;
        if (2 * t < NB)     pofs[2 * t]     = counts[(2 * t) * NBLK + blk] - excl;
        if (2 * t + 1 < NB) pofs[2 * t + 1] = counts[(2 * t + 1) * NBLK + blk] - (excl + a0);
        __syncthreads();
        for (int i = i0 + t; i < i1; i += 256) {
            int s, d, b;
            if (i < E) { s = ei1[i]; d = ei1[E + i]; b = d >> SH; }
            else       { s = ei2[i - E]; d = ei2[i]; b = (d >> SH) + nb; }
            int p = atomicAdd(&lpos[b], 1);
            int slot = lofs[b] + p;
            payload[slot] = ((unsigned)s << SH) | ((unsigned)d & (BK - 1));
            lbuck[slot] = (unsigned short)b;
        }
        __syncthreads();
        int total = i1 - i0;
        for (int sl = t; sl < total; sl += 256) {
            int b = lbuck[sl];
            int posg = pofs[b] + sl;
            if (posg < CAPB) bedge[(size_t)b * CAPB + posg] = payload[sl];
        }
    } else {
        for (int b = t; b < NB; b += 256) lpos[b] = counts[b * NBLK + blk];
        __syncthreads();
        for (int i = i0 + t; i < i1; i += 256) {
            int s, d, b;
            if (i < E) { s = ei1[i]; d = ei1[E + i]; b = d >> SH; }
            else       { s = ei2[i - E]; d = ei2[i]; b = (d >> SH) + nb; }
            int pos = atomicAdd(&lpos[b], 1);
            if (pos < CAPB)
                bedge[(size_t)b * CAPB + pos] = ((unsigned)s << SH) | ((unsigned)d & (BK - 1));
        }
    }
}

__global__ __launch_bounds__(256) void k_bucket2(
    const int* __restrict__ bfill1, const unsigned int* __restrict__ bedge1,
    int* __restrict__ rp1, int* __restrict__ dg1, int* __restrict__ col1,
    const int* __restrict__ bfill2, const unsigned int* __restrict__ bedge2,
    int* __restrict__ rp2, int* __restrict__ dg2, int* __restrict__ col2,
    int nb, int N)
{
    int b = blockIdx.x;
    const int* bfill; const unsigned int* bedge; int* rowptr; int* deg; int* col;
    if (b < nb) { bfill = bfill1; bedge = bedge1; rowptr = rp1; deg = dg1; col = col1; }
    else { b -= nb; bfill = bfill2; bedge = bedge2; rowptr = rp2; deg = dg2; col = col2; }

    __shared__ int ldeg[BK], lfill[BK];
    __shared__ int ps[256];
    int t = threadIdx.x;
    ldeg[2 * t] = 0; ldeg[2 * t + 1] = 0;
    __syncthreads();

    int cnt = min(bfill[b], CAPB);
    const unsigned int* be = bedge + (size_t)b * CAPB;
    for (int e = t; e < cnt; e += 256) atomicAdd(&ldeg[be[e] & (BK - 1)], 1);
    __syncthreads();

    int a0 = ldeg[2 * t], a1 = ldeg[2 * t + 1];
    ps[t] = a0 + a1;
    __syncthreads();
    #pragma unroll
    for (int off = 1; off < 256; off <<= 1) {
        int v = (t >= off) ? ps[t - off] : 0;
        __syncthreads();
        ps[t] += v;
        __syncthreads();
    }
    int excl = ps[t] - (a0 + a1);
    lfill[2 * t] = excl;
    lfill[2 * t + 1] = excl + a0;
    int node = (b << SH) + 2 * t;
    int base = b * CAPB;
    if (node < N)     { rowptr[node] = base + excl;      deg[node] = a0; }
    if (node + 1 < N) { rowptr[node + 1] = base + excl + a0; deg[node + 1] = a1; }
    __syncthreads();

    for (int e = t; e < cnt; e += 256) {
        unsigned int pk = be[e];
        int pos = atomicAdd(&lfill[pk & (BK - 1)], 1);
        col[base + pos] = (int)(pk >> SH);
    }
}

// ---------------- MFMA bf16 GEMM: A direct global->register, no per-tile barriers ----
// W staged once (vectorized, hoisted dtype branch, single barrier); A fragments
// loaded straight to registers (16B contiguous per lane); A1/A2 col-64 split is
// compile-time. Layouts (measured, m89/m120): A[m=lane&15][k=quad*8+j];
// B[k=quad*8+j][n=lane&15]; D col=lane&15, row=quad*4+reg. Hout is bf16.

template <int K, int C>
DEV void gemm_dev(int bid, int gstride,
    const void* __restrict__ A1, int mode1, const void* __restrict__ A2, int mode2,
    const void* __restrict__ Wr, const void* __restrict__ avr, const void* __restrict__ dvr,
    unsigned short* __restrict__ Hout, float* __restrict__ as_, float* __restrict__ ad_,
    int N, int numTiles)
{
    constexpr int KP = K + 8;
    constexpr int KK = K / 32;
    constexpr int CT = C / 16;

    __shared__ alignas(16) short Wt[C * KP];
    __shared__ float avs[C], dvs[C];

    int t = threadIdx.x;
    int f = 0;
    if (mode1) f = detect_bf16(A1);
    else if (mode2) f = detect_bf16(A2);
    int fW = detect_bf16(Wr);   // W arrays are >=2048 elems, safe to probe

    // Stage W[k][n] -> Wt[n*KP+k]; vectorized global reads, hoisted dtype branch.
    if (fW) {
        const ushort4* W4 = (const ushort4*)Wr;
        for (int i = t; i < K * C / 4; i += 256) {
            int k = (i * 4) / C, n = (i * 4) % C;
            ushort4 v = W4[i];
            Wt[(n + 0) * KP + k] = (short)v.x; Wt[(n + 1) * KP + k] = (short)v.y;
            Wt[(n + 2) * KP + k] = (short)v.z; Wt[(n + 3) * KP + k] = (short)v.w;
        }
    } else {
        const float4* W4 = (const float4*)Wr;
        for (int i = t; i < K * C / 4; i += 256) {
            int k = (i * 4) / C, n = (i * 4) % C;
            float4 v = W4[i];
            Wt[(n + 0) * KP + k] = (short)f2bf(v.x); Wt[(n + 1) * KP + k] = (short)f2bf(v.y);
            Wt[(n + 2) * KP + k] = (short)f2bf(v.z); Wt[(n + 3) * KP + k] = (short)f2bf(v.w);
        }
    }
    for (int i = t; i < C; i += 256) { avs[i] = ldf(avr, i, fW); dvs[i] = ldf(dvr, i, fW); }
    __syncthreads();   // only barrier: Wt/avs/dvs ready; Wt never rewritten

    const int lane = t & 63, w = t >> 6;
    const int m = lane & 15, q = lane >> 4;

    bf16x8 bfr[KK][CT];
    #pragma unroll
    for (int kk = 0; kk < KK; kk++)
        #pragma unroll
        for (int ct = 0; ct < CT; ct++)
            bfr[kk][ct] = *(const bf16x8*)&Wt[(ct * 16 + m) * KP + kk * 32 + q * 8];

    for (int tile = bid; tile < numTiles; tile += gstride) {
        int rowBase = tile * 64;
        int arow = rowBase + w * 16 + m;
        int rowc = arow < N ? arow : N - 1;   // clamp: overflow rows never stored

        bf16x8 afr[KK];
        #pragma unroll
        for (int kk = 0; kk < KK; kk++) {
            int koff = kk * 32 + q * 8;
            U4B8 u;
            if (kk * 32 < 64) u.u = ld8(A1, (size_t)rowc * 64 + koff, mode1, f);
            else              u.u = ld8(A2, (size_t)rowc * 64 + (koff - 64), mode2, f);
            afr[kk] = u.b;
        }

        f32x4 acc[CT];
        #pragma unroll
        for (int ct = 0; ct < CT; ct++) acc[ct] = (f32x4){0.f, 0.f, 0.f, 0.f};

        #pragma unroll
        for (int kk = 0; kk < KK; kk++)
            #pragma unroll
            for (int ct = 0; ct < CT; ct++)
                acc[ct] = __builtin_amdgcn_mfma_f32_16x16x32_bf16(afr[kk], bfr[kk][ct], acc[ct], 0, 0, 0);

        #pragma unroll
        for (int r = 0; r < 4; r++) {
            int grow = rowBase + w * 16 + q * 4 + r;
            float vs = 0.f, vd = 0.f;
            #pragma unroll
            for (int ct = 0; ct < CT; ct++) {
                float v = acc[ct][r];
                vs += v * avs[ct * 16 + m];
                vd += v * dvs[ct * 16 + m];
                if (grow < N) Hout[(size_t)grow * C + ct * 16 + m] = f2bf(v);
            }
            vs += __shfl_xor(vs, 1); vs += __shfl_xor(vs, 2);
            vs += __shfl_xor(vs, 4); vs += __shfl_xor(vs, 8);
            vd += __shfl_xor(vd, 1); vd += __shfl_xor(vd, 2);
            vd += __shfl_xor(vd, 4); vd += __shfl_xor(vd, 8);
            if (grow < N && m == 0) { as_[grow] = vs; ad_[grow] = vd; }
        }
    }
}

template <int K, int C>
__global__ __launch_bounds__(256) void k_gemm(
    const void* __restrict__ A1, int mode1, const void* __restrict__ A2, int mode2,
    const void* __restrict__ Wr, const void* __restrict__ avr, const void* __restrict__ dvr,
    unsigned short* __restrict__ Hout, float* __restrict__ as_, float* __restrict__ ad_,
    int N, int numTiles, int gstride)
{
    gemm_dev<K, C>(blockIdx.x, gstride, A1, mode1, A2, mode2, Wr, avr, dvr,
                   Hout, as_, ad_, N, numTiles);
}

// ---------------- Front: CSR-count || gemm0 || params in ONE launch ----------------
// Count blocks FIRST so count+gemm co-schedule from t=0.
// Blocks [0,NBLK) count ; [NBLK, NBLK+gT) gemm ; [NBLK+gT] params.

__global__ __launch_bounds__(256) void k_front(
    const void* __restrict__ x1,
    const int* __restrict__ ei1, const int* __restrict__ ei2, int E,
    int* __restrict__ counts, int nb, int NB, int chunk,
    const void* __restrict__ W0r, const void* __restrict__ as0r, const void* __restrict__ ad0r,
    unsigned short* __restrict__ hlin, float* __restrict__ as_, float* __restrict__ ad_,
    int N, int numTiles, int gT, Ptrs6 pp, float* __restrict__ P)
{
    int b = blockIdx.x;
    if (b < NBLK) {
        count_dev(b, ei1, ei2, E, counts, nb, NB, chunk);
    } else if (b < NBLK + gT) {
        gemm_dev<64, 64>(b - NBLK, gT, x1, 1, x1, 0, W0r, as0r, ad0r, hlin, as_, ad_, N, numTiles);
    } else {
        params_dev(pp, P);
    }
}

// ---------------- Aggregation F=64: 2 nodes per wave (32 lanes each) ----------------
// Per 32-lane half: 8 feature-lanes x 4 edge-groups, 16B gathers. Scalar fma
// (pk_fma f32x2 form measured +3us slower, round-9). Branchless (invalid slots
// have w=0, s=0 -> zero-weight FMA on row 0). Bulk/tail split: 16-edge macro
// iters while >=4 quads remain, then 8-edge cleanup — cuts the ~2x slot
// quantization waste for deg in (16,24] at unchanged MLP=4 bulk. `it` stays
// even so shuffle indices stay <= 31.

__global__ __launch_bounds__(256) void k_agg64(
    const int* __restrict__ rowptr, const int* __restrict__ deg,
    const int* __restrict__ col, const float* __restrict__ as_,
    const float* __restrict__ ad_, const unsigned short* __restrict__ h,
    const float* __restrict__ bias, unsigned short* __restrict__ out,
    int N, int doElu)
{
    int wid = (blockIdx.x * blockDim.x + threadIdx.x) >> 5;
    int lane = threadIdx.x & 31;
    if (wid >= N) return;
    int start = rowptr[wid];
    int d = deg[wid];
    float adi = ad_[wid];
    float eself = __expf(lrelu(as_[wid] + adi));

    int dc = min(d, 32);
    float w = 0.f; int s = 0;
    if (lane < dc) { s = col[start + lane]; w = __expf(lrelu(as_[s] + adi)); }
    float ssum = w;
    for (int j = lane + 32; j < d; j += 32)
        ssum += __expf(lrelu(as_[col[start + j]] + adi));
    #pragma unroll
    for (int off = 16; off; off >>= 1) ssum += __shfl_xor(ssum, off);
    float inv = 1.f / (ssum + eself + 1e-16f);
    w *= inv;

    int fq = lane & 7, eg = lane >> 3;
    float acc[8];
    #pragma unroll
    for (int k = 0; k < 8; k++) acc[k] = 0.f;

    if (eg == 0) {
        u16x8 hv = *(const u16x8*)(h + (size_t)wid * 64 + fq * 8);
        float en = eself * inv;
        #pragma unroll
        for (int k = 0; k < 8; k++) acc[k] = en * us2f(hv[k]);
    }
    {
        int iters = (dc + 3) >> 2;   // 1..8 quads
        int it = 0;
        for (; it + 4 <= iters; it += 4) {      // bulk: 16 edges, MLP=4
            int j0 = it * 4 + eg;               // it <= 4 -> j0+12 <= 31
            float w0 = __shfl(w, j0, 32);       int s0 = __shfl(s, j0, 32);
            float w1 = __shfl(w, j0 + 4, 32);   int s1 = __shfl(s, j0 + 4, 32);
            float w2 = __shfl(w, j0 + 8, 32);   int s2 = __shfl(s, j0 + 8, 32);
            float w3 = __shfl(w, j0 + 12, 32);  int s3 = __shfl(s, j0 + 12, 32);
            u16x8 hv0 = *(const u16x8*)(h + (size_t)s0 * 64 + fq * 8);
            u16x8 hv1 = *(const u16x8*)(h + (size_t)s1 * 64 + fq * 8);
            u16x8 hv2 = *(const u16x8*)(h + (size_t)s2 * 64 + fq * 8);
            u16x8 hv3 = *(const u16x8*)(h + (size_t)s3 * 64 + fq * 8);
            #pragma unroll
            for (int k = 0; k < 8; k++) acc[k] += w0 * us2f(hv0[k]);
            #pragma unroll
            for (int k = 0; k < 8; k++) acc[k] += w1 * us2f(hv1[k]);
            #pragma unroll
            for (int k = 0; k < 8; k++) acc[k] += w2 * us2f(hv2[k]);
            #pragma unroll
            for (int k = 0; k < 8; k++) acc[k] += w3 * us2f(hv3[k]);
        }
        for (; it < iters; it += 2) {           // tail: 8 edges, MLP=2
            int j0 = it * 4 + eg;               // it even, <= 6 -> j0+4 <= 31
            float w0 = __shfl(w, j0, 32);       int s0 = __shfl(s, j0, 32);
            float w1 = __shfl(w, j0 + 4, 32);   int s1 = __shfl(s, j0 + 4, 32);
            u16x8 hv0 = *(const u16x8*)(h + (size_t)s0 * 64 + fq * 8);
            u16x8 hv1 = *(const u16x8*)(h + (size_t)s1 * 64 + fq * 8);
            #pragma unroll
            for (int k = 0; k < 8; k++) acc[k] += w0 * us2f(hv0[k]);
            #pragma unroll
            for (int k = 0; k < 8; k++) acc[k] += w1 * us2f(hv1[k]);
        }
    }
    for (int base = 32; base < d; base += 32) {
        int cnt = min(32, d - base);
        float wx = 0.f; int sx = 0;
        if (lane < cnt) { sx = col[start + base + lane]; wx = __expf(lrelu(as_[sx] + adi)) * inv; }
        int iters = (cnt + 3) >> 2;
        for (int it = 0; it < iters; it += 2) {
            int j0 = it * 4 + eg;
            float w0 = __shfl(wx, j0, 32);      int s0 = __shfl(sx, j0, 32);
            float w1 = __shfl(wx, j0 + 4, 32);  int s1 = __shfl(sx, j0 + 4, 32);
            u16x8 hv0 = *(const u16x8*)(h + (size_t)s0 * 64 + fq * 8);
            u16x8 hv1 = *(const u16x8*)(h + (size_t)s1 * 64 + fq * 8);
            #pragma unroll
            for (int k = 0; k < 8; k++) acc[k] += w0 * us2f(hv0[k]);
            #pragma unroll
            for (int k = 0; k < 8; k++) acc[k] += w1 * us2f(hv1[k]);
        }
    }
    #pragma unroll
    for (int k = 0; k < 8; k++) {
        acc[k] += __shfl_xor(acc[k], 8);
        acc[k] += __shfl_xor(acc[k], 16);
    }
    if (lane < 8) {
        float4 b0 = ((const float4*)bias)[lane * 2];
        float4 b1 = ((const float4*)bias)[lane * 2 + 1];
        float bb[8] = {b0.x, b0.y, b0.z, b0.w, b1.x, b1.y, b1.z, b1.w};
        u16x8 ob;
        #pragma unroll
        for (int k = 0; k < 8; k++) {
            float o = acc[k] + bb[k];
            if (doElu) o = eluf(o);
            ob[k] = f2bf(o);
        }
        *(u16x8*)(out + (size_t)wid * 64 + lane * 8) = ob;
    }
}

// ---------------- Aggregation F=16: 2 nodes per wave (bf16 in, fp32 out) ----------------
// Bulk/tail split like agg64: full 32-edge unroll only when all 4 groups are
// needed (dc>24), else 16-edge tail iterations — halves gather work for dc<=16.

__global__ __launch_bounds__(256) void k_agg16(
    const int* __restrict__ rowptr, const int* __restrict__ deg,
    const int* __restrict__ col, const float* __restrict__ as_,
    const float* __restrict__ ad_, const unsigned short* __restrict__ h,
    const float* __restrict__ bias, float* __restrict__ out, int N)
{
    int wid = (blockIdx.x * blockDim.x + threadIdx.x) >> 5;
    int lane = threadIdx.x & 31;
    if (wid >= N) return;
    int start = rowptr[wid];
    int d = deg[wid];
    float adi = ad_[wid];
    float eself = __expf(lrelu(as_[wid] + adi));

    int dc = min(d, 32);
    float w = 0.f; int s = 0;
    if (lane < dc) { s = col[start + lane]; w = __expf(lrelu(as_[s] + adi)); }
    float ssum = w;
    for (int j = lane + 32; j < d; j += 32)
        ssum += __expf(lrelu(as_[col[start + j]] + adi));
    #pragma unroll
    for (int off = 16; off; off >>= 1) ssum += __shfl_xor(ssum, off);
    float inv = 1.f / (ssum + eself + 1e-16f);
    w *= inv;

    int fq = lane & 3, eg = lane >> 2;
    float4 acc = {0.f, 0.f, 0.f, 0.f};
    if (eg == 0) {
        ushort4 hv = *(const ushort4*)(h + (size_t)wid * 16 + fq * 4);
        float en = eself * inv;
        acc.x = en * us2f(hv.x); acc.y = en * us2f(hv.y);
        acc.z = en * us2f(hv.z); acc.w = en * us2f(hv.w);
    }
    {
        int iters = (dc + 7) >> 3;   // 1..4 groups of 8 edges
        int it = 0;
        for (; it + 4 <= iters; it += 4) {      // bulk: all 32 edges (dc>24)
            float w0 = __shfl(w, eg, 32);       int s0 = __shfl(s, eg, 32);
            float w1 = __shfl(w, eg + 8, 32);   int s1 = __shfl(s, eg + 8, 32);
            float w2 = __shfl(w, eg + 16, 32);  int s2 = __shfl(s, eg + 16, 32);
            float w3 = __shfl(w, eg + 24, 32);  int s3 = __shfl(s, eg + 24, 32);
            ushort4 hv0 = *(const ushort4*)(h + (size_t)s0 * 16 + fq * 4);
            ushort4 hv1 = *(const ushort4*)(h + (size_t)s1 * 16 + fq * 4);
            ushort4 hv2 = *(const ushort4*)(h + (size_t)s2 * 16 + fq * 4);
            ushort4 hv3 = *(const ushort4*)(h + (size_t)s3 * 16 + fq * 4);
            acc.x += w0 * us2f(hv0.x); acc.y += w0 * us2f(hv0.y);
            acc.z += w0 * us2f(hv0.z); acc.w += w0 * us2f(hv0.w);
            acc.x += w1 * us2f(hv1.x); acc.y += w1 * us2f(hv1.y);
            acc.z += w1 * us2f(hv1.z); acc.w += w1 * us2f(hv1.w);
            acc.x += w2 * us2f(hv2.x); acc.y += w2 * us2f(hv2.y);
            acc.z += w2 * us2f(hv2.z); acc.w += w2 * us2f(hv2.w);
            acc.x += w3 * us2f(hv3.x); acc.y += w3 * us2f(hv3.y);
            acc.z += w3 * us2f(hv3.z); acc.w += w3 * us2f(hv3.w);
        }
        for (; it < iters; it += 2) {           // tail: 16 edges
            int j0 = it * 8 + eg;               // it even, <= 2 -> j0+8 <= 31
            float w0 = __shfl(w, j0, 32);       int s0 = __shfl(s, j0, 32);
            float w1 = __shfl(w, j0 + 8, 32);   int s1 = __shfl(s, j0 + 8, 32);
            ushort4 hv0 = *(const ushort4*)(h + (size_t)s0 * 16 + fq * 4);
            ushort4 hv1 = *(const ushort4*)(h + (size_t)s1 * 16 + fq * 4);
            acc.x += w0 * us2f(hv0.x); acc.y += w0 * us2f(hv0.y);
            acc.z += w0 * us2f(hv0.z); acc.w += w0 * us2f(hv0.w);
            acc.x += w1 * us2f(hv1.x); acc.y += w1 * us2f(hv1.y);
            acc.z += w1 * us2f(hv1.z); acc.w += w1 * us2f(hv1.w);
        }
    }
    for (int base = 32; base < d; base += 32) {
        int cnt = min(32, d - base);
        float wy = 0.f; int sy = 0;
        if (lane < cnt) { sy = col[start + base + lane]; wy = __expf(lrelu(as_[sy] + adi)) * inv; }
        int iters = (cnt + 7) >> 3;
        for (int it = 0; it < iters; it += 2) {
            int j0 = it * 8 + eg;
            float w0 = __shfl(wy, j0, 32);      int s0 = __shfl(sy, j0, 32);
            float w1 = __shfl(wy, j0 + 8, 32);  int s1 = __shfl(sy, j0 + 8, 32);
            ushort4 hv0 = *(const ushort4*)(h + (size_t)s0 * 16 + fq * 4);
            ushort4 hv1 = *(const ushort4*)(h + (size_t)s1 * 16 + fq * 4);
            acc.x += w0 * us2f(hv0.x); acc.y += w0 * us2f(hv0.y);
            acc.z += w0 * us2f(hv0.z); acc.w += w0 * us2f(hv0.w);
            acc.x += w1 * us2f(hv1.x); acc.y += w1 * us2f(hv1.y);
            acc.z += w1 * us2f(hv1.z); acc.w += w1 * us2f(hv1.w);
        }
    }
    #pragma unroll
    for (int off = 4; off < 32; off <<= 1) {
        acc.x += __shfl_xor(acc.x, off);
        acc.y += __shfl_xor(acc.y, off);
        acc.z += __shfl_xor(acc.z, off);
        acc.w += __shfl_xor(acc.w, off);
    }
    if (lane < 4) {
        float4 b4 = ((const float4*)bias)[lane];
        float4 o = {acc.x + b4.x, acc.y + b4.y, acc.z + b4.z, acc.w + b4.w};
        ((float4*)out)[(size_t)wid * 4 + lane] = o;
    }
}

// ---------------- BatchNorm stats ----------------

__global__ __launch_bounds__(256) void k_bnstat(const float* __restrict__ logits,
                                                float* __restrict__ bn, int N) {
    int t = threadIdx.x;
    int c = t & 15;
    int g = (blockIdx.x * blockDim.x + t) >> 4;
    int stride = (gridDim.x * blockDim.x) >> 4;
    float s = 0.f, s2 = 0.f;
    for (int r = g; r < N; r += stride) {
        float v = logits[r * 16 + c];
        s += v;
        s2 += v * v;
    }
    s += __shfl_xor(s, 16);  s += __shfl_xor(s, 32);
    s2 += __shfl_xor(s2, 16); s2 += __shfl_xor(s2, 32);
    if ((t & 63) < 16) {
        atomicAdd(&bn[c], s);
        atomicAdd(&bn[16 + c], s2);
    }
}

// ---------------- BN apply + log_softmax + out (dtype-branched) ----------------

__global__ __launch_bounds__(256) void k_final(
    const float* __restrict__ logits, const float* __restrict__ bn,
    const float* __restrict__ gamma, const float* __restrict__ beta,
    const void* __restrict__ x1, void* __restrict__ out, int N)
{
    int f = detect_bf16(x1);
    int r = blockIdx.x * blockDim.x + threadIdx.x;
    if (r >= N) return;
    float invN = 1.f / (float)N;
    float y[16];
    float mx = -1e30f;
    #pragma unroll
    for (int c = 0; c < 16; c++) {
        float mu = bn[c] * invN;
        float var = bn[16 + c] * invN - mu * mu;
        float v = (logits[r * 16 + c] - mu) * rsqrtf(var + 1e-5f);
        v = v * gamma[c] + beta[c];
        y[c] = v;
        mx = fmaxf(mx, v);
    }
    float se = 0.f;
    #pragma unroll
    for (int c = 0; c < 16; c++) se += __expf(y[c] - mx);
    float lse = mx + __logf(se);
    #pragma unroll
    for (int c = 0; c < 16; c++) {
        float v = y[c] - lse;
        if (f) ((__hip_bfloat16*)out)[r * 16 + c] = __float2bfloat16(v);
        else   ((float*)out)[r * 16 + c] = v;
    }
}

// ---------------- launch ----------------

extern "C" void kernel_launch(void* const* d_in, const int* in_sizes, int n_in,
                              void* d_out, int out_size, void* d_ws, size_t ws_size,
                              hipStream_t stream) {
    const void* x1  = d_in[0];
    const void* x2  = d_in[1];
    const int*  ei1 = (const int*)d_in[2];
    const int*  ei2 = (const int*)d_in[3];

    const int N = in_sizes[0] / 64;
    const int E = in_sizes[2] / 2;
    const int nb = (N + BK - 1) >> SH;   // 512-node buckets
    const int NB = 2 * nb;
    const int chunk = (2 * E + NBLK - 1) / NBLK;

    char* p = (char*)d_ws;
    auto alloc = [&](size_t bytes) {
        void* q = (void*)p;
        p += (bytes + 255) & ~(size_t)255;
        return q;
    };
    float* bn       = (float*)alloc(256);                   // zeroed by memset
    unsigned short* h0 = (unsigned short*)alloc((size_t)N * 64 * 2);  // bf16
    unsigned short* h1 = (unsigned short*)alloc((size_t)N * 64 * 2);  // bf16
    unsigned short* hlin = (unsigned short*)alloc((size_t)N * 64 * 2);  // bf16
    float* as_      = (float*)alloc((size_t)N * 4);
    float* ad_      = (float*)alloc((size_t)N * 4);
    int* rowptr1    = (int*)alloc((size_t)N * 4);
    int* deg1       = (int*)alloc((size_t)N * 4);
    int* rowptr2    = (int*)alloc((size_t)N * 4);
    int* deg2       = (int*)alloc((size_t)N * 4);
    int* col1       = (int*)alloc((size_t)nb * CAPB * 4);   // aliased as logits later
    int* col2       = (int*)alloc((size_t)nb * CAPB * 4);
    int* counts     = (int*)alloc((size_t)NB * NBLK * 4);
    int* bfill      = (int*)alloc((size_t)NB * 4);
    float* P        = (float*)alloc(P_TOTAL * 4);
    float* logits   = (float*)col1;  // col1 dead after layer-0 agg

    // bedge (packed uint, NB*CAPB*4 = ~19.3MB) aliases h0/h1 head (25.6MB).
    // Safe: bedge fully consumed by k_bucket2 before any h0/h1 write; front's
    // gemm0 writes only hlin/as_/ad_ which do NOT overlap bedge.
    unsigned int* bedge   = (unsigned int*)h0;
    unsigned int* bedge2p = bedge + (size_t)nb * CAPB;

    hipMemsetAsync(bn, 0, 256, stream);

    const int TB = 256;
    int gN = (N + TB - 1) / TB;
    int gW = (N + 7) / 8;       // 2 nodes per wave, 8 nodes per 256-thr block
    int nt = (N + 63) / 64;
    int gT = nt < 1024 ? nt : 1024;   // short streaming blocks, 1-2 tiles each

    Ptrs6 pp;
    pp.p[0] = d_in[7];   // b0
    pp.p[1] = d_in[11];  // b1
    pp.p[2] = d_in[15];  // b2
    pp.p[3] = d_in[16];  // gamma
    pp.p[4] = d_in[17];  // beta
    pp.p[5] = x1;        // dtype probe

    // Front: CSR count || layer-0 GEMM || params (independent; count first)
    k_front<<<NBLK + gT + 1, TB, 0, stream>>>(
        x1, ei1, ei2, E, counts, nb, NB, chunk,
        d_in[4], d_in[5], d_in[6], hlin, as_, ad_, N, nt, gT, pp, P);

    // CSR: scan -> place (LDS-reordered) -> per-bucket node sort
    k_scan<<<NB, TB, 0, stream>>>(counts, bfill);
    k_place<<<NBLK, TB, 0, stream>>>(ei1, ei2, E, counts, bedge, nb, NB, chunk);
    k_bucket2<<<NB, TB, 0, stream>>>(bfill, bedge, rowptr1, deg1, col1,
                                     bfill + nb, bedge2p, rowptr2, deg2, col2, nb, N);

    // Layer 0 aggregate: graph1 -> h0 (elu, bf16)
    k_agg64<<<gW, TB, 0, stream>>>(rowptr1, deg1, col1, as_, ad_, hlin, P + P_B0, h0, N, 1);

    // Layer 1: [h0 bf16 | x2 raw] @ W1 -> hlin (bf16); aggregate graph2 -> h1
    k_gemm<128, 64><<<gT, TB, 0, stream>>>(
        h0, 0, x2, 1, d_in[8], d_in[9], d_in[10], hlin, as_, ad_, N, nt, gT);
    k_agg64<<<gW, TB, 0, stream>>>(rowptr2, deg2, col2, as_, ad_, hlin, P + P_B1, h1, N, 1);

    // Layer 2: [h0 | h1] @ W2 -> hlin(:,:16); aggregate graph2 -> logits (fp32)
    k_gemm<128, 16><<<gT, TB, 0, stream>>>(
        h0, 0, h1, 0, d_in[12], d_in[13], d_in[14], hlin, as_, ad_, N, nt, gT);
    k_agg16<<<gW, TB, 0, stream>>>(rowptr2, deg2, col2, as_, ad_, hlin, P + P_B2, logits, N);

    // BN + log_softmax
    k_bnstat<<<256, TB, 0, stream>>>(logits, bn, N);
    k_final<<<gN, TB, 0, stream>>>(logits, bn, P + P_GAMMA, P + P_BETA, x1, d_out, N);
}

// Round 11
// 350.642 us; speedup vs baseline: 1.0353x; 1.0353x over previous
//
#include <hip/hip_runtime.h>
#include <hip/hip_bf16.h>

#define DEV __device__ __forceinline__

typedef __attribute__((ext_vector_type(8))) short bf16x8;
typedef __attribute__((ext_vector_type(8))) unsigned short u16x8;
typedef __attribute__((ext_vector_type(4))) float f32x4;

union U4B8 { uint4 u; bf16x8 b; };

DEV float bf2f(__hip_bfloat16 v) { return __bfloat162float(v); }
DEV float us2f(unsigned short u) { return __uint_as_float(((unsigned)u) << 16); }
DEV float lrelu(float x) { return x > 0.f ? x : 0.2f * x; }
DEV float eluf(float x) { return x > 0.f ? x : (__expf(x) - 1.f); }

// fp32 -> bf16 bits, round-to-nearest-even
DEV unsigned short f2bf(float x) {
    unsigned int u = __float_as_uint(x);
    return (unsigned short)((u + 0x7FFFu + ((u >> 16) & 1u)) >> 16);
}

// Read element i of a float tensor that is either bf16 (f=1) or fp32 (f=0).
DEV float ldf(const void* p, int i, int f) {
    return f ? bf2f(((const __hip_bfloat16*)p)[i]) : ((const float*)p)[i];
}

// Inline dtype detection: bf16 low-half exponent test, 64 samples.
// Only call on arrays >= 256B (64 u32 samples).
DEV int detect_bf16(const void* p) {
    const unsigned int* w = (const unsigned int*)p;
    unsigned int e = (w[threadIdx.x & 63] >> 7) & 0xFFu;
    int hit = (e >= 112u && e <= 130u) ? 1 : 0;
    unsigned long long b = __ballot(hit);
    return __popcll(b) > 32 ? 1 : 0;
}

// Load 8 consecutive "float" elems as 8 packed bf16 (16B).
// mode==0: src is our own bf16 buffer. mode==1: raw input, branch on f.
DEV uint4 ld8(const void* src, size_t off, int mode, int f) {
    if (mode == 0 || f) return *(const uint4*)((const unsigned short*)src + off);
    const float* s = (const float*)src + off;
    float4 a = *(const float4*)s, b = *(const float4*)(s + 4);
    uint4 r;
    r.x = f2bf(a.x) | ((unsigned)f2bf(a.y) << 16);
    r.y = f2bf(a.z) | ((unsigned)f2bf(a.w) << 16);
    r.z = f2bf(b.x) | ((unsigned)f2bf(b.y) << 16);
    r.w = f2bf(b.z) | ((unsigned)f2bf(b.w) << 16);
    return r;
}

// ---------------- P buffer: biases + BN params only (weights read raw) ----------------

struct Ptrs6 { const void* p[6]; };  // b0,b1,b2,gamma,beta,[5]=x1 for detect

#define P_B0 0
#define P_B1 64
#define P_B2 128
#define P_GAMMA 144
#define P_BETA 160
#define P_TOTAL 176

DEV void params_dev(Ptrs6 pp, float* __restrict__ P) {
    const int narr[5] = {64, 64, 16, 16, 16};
    const int oarr[5] = {P_B0, P_B1, P_B2, P_GAMMA, P_BETA};
    int f = detect_bf16(pp.p[5]);
    for (int a = 0; a < 5; a++)
        for (int i = threadIdx.x; i < narr[a]; i += 256)
            P[oarr[a] + i] = ldf(pp.p[a], i, f);
}

// ---------------- CSR build: contention-free 3-phase bucket sort ----------------
// Buckets are 512 nodes (SH=9). bedge entry packed: (src << 9) | (dst & 511).
// Valid while N < 2^23. k_place reorders its chunk through LDS so bedge
// writes go out as per-bucket contiguous runs instead of scattered 4B stores.
// NBLK=1024: halved chunk halves the serial chain, ~29KB LDS fits ~5 blk/CU.

#define SH 9
#define BK 512
#define CAPB 12288
#define NBLK 1024
#define NBMX 512
#define CHUNK_MAX 3328

DEV void count_dev(int blk, const int* __restrict__ ei1, const int* __restrict__ ei2,
                   int E, int* __restrict__ counts, int nb, int NB, int chunk)
{
    __shared__ int lcnt[NBMX];
    int t = threadIdx.x;
    for (int b = t; b < NB; b += 256) lcnt[b] = 0;
    __syncthreads();
    int i0 = blk * chunk, i1 = min(i0 + chunk, 2 * E);
    for (int i = i0 + t; i < i1; i += 256) {
        int b;
        if (i < E) b = ei1[E + i] >> SH;
        else       b = (ei2[i] >> SH) + nb;
        atomicAdd(&lcnt[b], 1);
    }
    __syncthreads();
    for (int b = t; b < NB; b += 256) counts[b * NBLK + blk] = lcnt[b];
}

__global__ __launch_bounds__(256) void k_scan(
    int* __restrict__ counts, int* __restrict__ bfill)
{
    int b = blockIdx.x, t = threadIdx.x;
    __shared__ int ps[256];
    int* row = counts + b * NBLK;
    int x0 = row[4 * t], x1 = row[4 * t + 1], x2 = row[4 * t + 2], x3 = row[4 * t + 3];
    int sum = x0 + x1 + x2 + x3;
    ps[t] = sum;
    __syncthreads();
    #pragma unroll
    for (int off = 1; off < 256; off <<= 1) {
        int v = (t >= off) ? ps[t - off] : 0;
        __syncthreads();
        ps[t] += v;
        __syncthreads();
    }
    int excl = ps[t] - sum;
    row[4 * t]     = excl;
    row[4 * t + 1] = excl + x0;
    row[4 * t + 2] = excl + x0 + x1;
    row[4 * t + 3] = excl + x0 + x1 + x2;
    if (t == 255) bfill[b] = ps[255];
}

__global__ __launch_bounds__(256) void k_place(
    const int* __restrict__ ei1, const int* __restrict__ ei2, int E,
    const int* __restrict__ counts, unsigned int* __restrict__ bedge,
    int nb, int NB, int chunk)
{
    __shared__ unsigned int payload[CHUNK_MAX];
    __shared__ unsigned short lbuck[CHUNK_MAX];
    __shared__ int lcnt[NBMX], lofs[NBMX], lpos[NBMX], pofs[NBMX];
    __shared__ int ps[256];
    int t = threadIdx.x, blk = blockIdx.x;
    int i0 = blk * chunk, i1 = min(i0 + chunk, 2 * E);

    if (chunk <= CHUNK_MAX && NB <= NBMX) {
        for (int b = t; b < NBMX; b += 256) { lcnt[b] = 0; lpos[b] = 0; }
        __syncthreads();
        for (int i = i0 + t; i < i1; i += 256) {
            int b;
            if (i < E) b = ei1[E + i] >> SH;
            else       b = (ei2[i] >> SH) + nb;
            atomicAdd(&lcnt[b], 1);
        }
        __syncthreads();
        int a0 = lcnt[2 * t], a1 = lcnt[2 * t + 1];
        ps[t] = a0 + a1;
        __syncthreads();
        #pragma unroll
        for (int off = 1; off < 256; off <<= 1) {
            int v = (t >= off) ? ps[t - off] : 0;
            __syncthreads();
            ps[t] += v;
            __syncthreads();
        }
        int excl = ps[t] - (a0 + a1);
        lofs[2 * t] = excl;
        lofs[2 * t + 1] = excl + a0;
        if (2 * t < NB)     pofs[2 * t]     = counts[(2 * t) * NBLK + blk] - excl;
        if (2 * t + 1 < NB) pofs[2 * t + 1] = counts[(2 * t + 1) * NBLK + blk] - (excl + a0);
        __syncthreads();
        for (int i = i0 + t; i < i1; i += 256) {
            int s, d, b;
            if (i < E) { s = ei1[i]; d = ei1[E + i]; b = d >> SH; }
            else       { s = ei2[i - E]; d = ei2[i]; b = (d >> SH) + nb; }
            int p = atomicAdd(&lpos[b], 1);
            int slot = lofs[b] + p;
            payload[slot] = ((unsigned)s << SH) | ((unsigned)d & (BK - 1));
            lbuck[slot] = (unsigned short)b;
        }
        __syncthreads();
        int total = i1 - i0;
        for (int sl = t; sl < total; sl += 256) {
            int b = lbuck[sl];
            int posg = pofs[b] + sl;
            if (posg < CAPB) bedge[(size_t)b * CAPB + posg] = payload[sl];
        }
    } else {
        for (int b = t; b < NB; b += 256) lpos[b] = counts[b * NBLK + blk];
        __syncthreads();
        for (int i = i0 + t; i < i1; i += 256) {
            int s, d, b;
            if (i < E) { s = ei1[i]; d = ei1[E + i]; b = d >> SH; }
            else       { s = ei2[i - E]; d = ei2[i]; b = (d >> SH) + nb; }
            int pos = atomicAdd(&lpos[b], 1);
            if (pos < CAPB)
                bedge[(size_t)b * CAPB + pos] = ((unsigned)s << SH) | ((unsigned)d & (BK - 1));
        }
    }
}

__global__ __launch_bounds__(256) void k_bucket2(
    const int* __restrict__ bfill1, const unsigned int* __restrict__ bedge1,
    int* __restrict__ rp1, int* __restrict__ dg1, int* __restrict__ col1,
    const int* __restrict__ bfill2, const unsigned int* __restrict__ bedge2,
    int* __restrict__ rp2, int* __restrict__ dg2, int* __restrict__ col2,
    int nb, int N)
{
    int b = blockIdx.x;
    const int* bfill; const unsigned int* bedge; int* rowptr; int* deg; int* col;
    if (b < nb) { bfill = bfill1; bedge = bedge1; rowptr = rp1; deg = dg1; col = col1; }
    else { b -= nb; bfill = bfill2; bedge = bedge2; rowptr = rp2; deg = dg2; col = col2; }

    __shared__ int ldeg[BK], lfill[BK];
    __shared__ int ps[256];
    int t = threadIdx.x;
    ldeg[2 * t] = 0; ldeg[2 * t + 1] = 0;
    __syncthreads();

    int cnt = min(bfill[b], CAPB);
    const unsigned int* be = bedge + (size_t)b * CAPB;
    for (int e = t; e < cnt; e += 256) atomicAdd(&ldeg[be[e] & (BK - 1)], 1);
    __syncthreads();

    int a0 = ldeg[2 * t], a1 = ldeg[2 * t + 1];
    ps[t] = a0 + a1;
    __syncthreads();
    #pragma unroll
    for (int off = 1; off < 256; off <<= 1) {
        int v = (t >= off) ? ps[t - off] : 0;
        __syncthreads();
        ps[t] += v;
        __syncthreads();
    }
    int excl = ps[t] - (a0 + a1);
    lfill[2 * t] = excl;
    lfill[2 * t + 1] = excl + a0;
    int node = (b << SH) + 2 * t;
    int base = b * CAPB;
    if (node < N)     { rowptr[node] = base + excl;      deg[node] = a0; }
    if (node + 1 < N) { rowptr[node + 1] = base + excl + a0; deg[node + 1] = a1; }
    __syncthreads();

    for (int e = t; e < cnt; e += 256) {
        unsigned int pk = be[e];
        int pos = atomicAdd(&lfill[pk & (BK - 1)], 1);
        col[base + pos] = (int)(pk >> SH);
    }
}

// ---------------- MFMA bf16 GEMM: A direct global->register, no per-tile barriers ----
// W staged once (vectorized, hoisted dtype branch, single barrier); A fragments
// loaded straight to registers (16B contiguous per lane); A1/A2 col-64 split is
// compile-time. Layouts (measured, m89/m120): A[m=lane&15][k=quad*8+j];
// B[k=quad*8+j][n=lane&15]; D col=lane&15, row=quad*4+reg. Hout is bf16.

template <int K, int C>
DEV void gemm_dev(int bid, int gstride,
    const void* __restrict__ A1, int mode1, const void* __restrict__ A2, int mode2,
    const void* __restrict__ Wr, const void* __restrict__ avr, const void* __restrict__ dvr,
    unsigned short* __restrict__ Hout, float* __restrict__ as_, float* __restrict__ ad_,
    int N, int numTiles)
{
    constexpr int KP = K + 8;
    constexpr int KK = K / 32;
    constexpr int CT = C / 16;

    __shared__ alignas(16) short Wt[C * KP];
    __shared__ float avs[C], dvs[C];

    int t = threadIdx.x;
    int f = 0;
    if (mode1) f = detect_bf16(A1);
    else if (mode2) f = detect_bf16(A2);
    int fW = detect_bf16(Wr);   // W arrays are >=2048 elems, safe to probe

    // Stage W[k][n] -> Wt[n*KP+k]; vectorized global reads, hoisted dtype branch.
    if (fW) {
        const ushort4* W4 = (const ushort4*)Wr;
        for (int i = t; i < K * C / 4; i += 256) {
            int k = (i * 4) / C, n = (i * 4) % C;
            ushort4 v = W4[i];
            Wt[(n + 0) * KP + k] = (short)v.x; Wt[(n + 1) * KP + k] = (short)v.y;
            Wt[(n + 2) * KP + k] = (short)v.z; Wt[(n + 3) * KP + k] = (short)v.w;
        }
    } else {
        const float4* W4 = (const float4*)Wr;
        for (int i = t; i < K * C / 4; i += 256) {
            int k = (i * 4) / C, n = (i * 4) % C;
            float4 v = W4[i];
            Wt[(n + 0) * KP + k] = (short)f2bf(v.x); Wt[(n + 1) * KP + k] = (short)f2bf(v.y);
            Wt[(n + 2) * KP + k] = (short)f2bf(v.z); Wt[(n + 3) * KP + k] = (short)f2bf(v.w);
        }
    }
    for (int i = t; i < C; i += 256) { avs[i] = ldf(avr, i, fW); dvs[i] = ldf(dvr, i, fW); }
    __syncthreads();   // only barrier: Wt/avs/dvs ready; Wt never rewritten

    const int lane = t & 63, w = t >> 6;
    const int m = lane & 15, q = lane >> 4;

    bf16x8 bfr[KK][CT];
    #pragma unroll
    for (int kk = 0; kk < KK; kk++)
        #pragma unroll
        for (int ct = 0; ct < CT; ct++)
            bfr[kk][ct] = *(const bf16x8*)&Wt[(ct * 16 + m) * KP + kk * 32 + q * 8];

    for (int tile = bid; tile < numTiles; tile += gstride) {
        int rowBase = tile * 64;
        int arow = rowBase + w * 16 + m;
        int rowc = arow < N ? arow : N - 1;   // clamp: overflow rows never stored

        bf16x8 afr[KK];
        #pragma unroll
        for (int kk = 0; kk < KK; kk++) {
            int koff = kk * 32 + q * 8;
            U4B8 u;
            if (kk * 32 < 64) u.u = ld8(A1, (size_t)rowc * 64 + koff, mode1, f);
            else              u.u = ld8(A2, (size_t)rowc * 64 + (koff - 64), mode2, f);
            afr[kk] = u.b;
        }

        f32x4 acc[CT];
        #pragma unroll
        for (int ct = 0; ct < CT; ct++) acc[ct] = (f32x4){0.f, 0.f, 0.f, 0.f};

        #pragma unroll
        for (int kk = 0; kk < KK; kk++)
            #pragma unroll
            for (int ct = 0; ct < CT; ct++)
                acc[ct] = __builtin_amdgcn_mfma_f32_16x16x32_bf16(afr[kk], bfr[kk][ct], acc[ct], 0, 0, 0);

        #pragma unroll
        for (int r = 0; r < 4; r++) {
            int grow = rowBase + w * 16 + q * 4 + r;
            float vs = 0.f, vd = 0.f;
            #pragma unroll
            for (int ct = 0; ct < CT; ct++) {
                float v = acc[ct][r];
                vs += v * avs[ct * 16 + m];
                vd += v * dvs[ct * 16 + m];
                if (grow < N) Hout[(size_t)grow * C + ct * 16 + m] = f2bf(v);
            }
            vs += __shfl_xor(vs, 1); vs += __shfl_xor(vs, 2);
            vs += __shfl_xor(vs, 4); vs += __shfl_xor(vs, 8);
            vd += __shfl_xor(vd, 1); vd += __shfl_xor(vd, 2);
            vd += __shfl_xor(vd, 4); vd += __shfl_xor(vd, 8);
            if (grow < N && m == 0) { as_[grow] = vs; ad_[grow] = vd; }
        }
    }
}

template <int K, int C>
__global__ __launch_bounds__(256) void k_gemm(
    const void* __restrict__ A1, int mode1, const void* __restrict__ A2, int mode2,
    const void* __restrict__ Wr, const void* __restrict__ avr, const void* __restrict__ dvr,
    unsigned short* __restrict__ Hout, float* __restrict__ as_, float* __restrict__ ad_,
    int N, int numTiles, int gstride)
{
    gemm_dev<K, C>(blockIdx.x, gstride, A1, mode1, A2, mode2, Wr, avr, dvr,
                   Hout, as_, ad_, N, numTiles);
}

// ---------------- Front: CSR-count || gemm0 || params in ONE launch ----------------
// Count blocks FIRST so count+gemm co-schedule from t=0.
// Blocks [0,NBLK) count ; [NBLK, NBLK+gT) gemm ; [NBLK+gT] params.

__global__ __launch_bounds__(256) void k_front(
    const void* __restrict__ x1,
    const int* __restrict__ ei1, const int* __restrict__ ei2, int E,
    int* __restrict__ counts, int nb, int NB, int chunk,
    const void* __restrict__ W0r, const void* __restrict__ as0r, const void* __restrict__ ad0r,
    unsigned short* __restrict__ hlin, float* __restrict__ as_, float* __restrict__ ad_,
    int N, int numTiles, int gT, Ptrs6 pp, float* __restrict__ P)
{
    int b = blockIdx.x;
    if (b < NBLK) {
        count_dev(b, ei1, ei2, E, counts, nb, NB, chunk);
    } else if (b < NBLK + gT) {
        gemm_dev<64, 64>(b - NBLK, gT, x1, 1, x1, 0, W0r, as0r, ad0r, hlin, as_, ad_, N, numTiles);
    } else {
        params_dev(pp, P);
    }
}

// ---------------- Aggregation F=64: 2 nodes per wave (32 lanes each) ----------------
// Per 32-lane half: 8 feature-lanes x 4 edge-groups, 16B gathers. Plain
// branchless unroll-4 (round-7 measured best: 40.9us; bulk/tail split and
// pk_fma variants both measured SLOWER — static simplicity wins in this
// latency-bound gather loop). Invalid slots have w=0, s=0 -> zero-weight FMA
// on row 0.

__global__ __launch_bounds__(256) void k_agg64(
    const int* __restrict__ rowptr, const int* __restrict__ deg,
    const int* __restrict__ col, const float* __restrict__ as_,
    const float* __restrict__ ad_, const unsigned short* __restrict__ h,
    const float* __restrict__ bias, unsigned short* __restrict__ out,
    int N, int doElu)
{
    int wid = (blockIdx.x * blockDim.x + threadIdx.x) >> 5;
    int lane = threadIdx.x & 31;
    if (wid >= N) return;
    int start = rowptr[wid];
    int d = deg[wid];
    float adi = ad_[wid];
    float eself = __expf(lrelu(as_[wid] + adi));

    int dc = min(d, 32);
    float w = 0.f; int s = 0;
    if (lane < dc) { s = col[start + lane]; w = __expf(lrelu(as_[s] + adi)); }
    float ssum = w;
    for (int j = lane + 32; j < d; j += 32)
        ssum += __expf(lrelu(as_[col[start + j]] + adi));
    #pragma unroll
    for (int off = 16; off; off >>= 1) ssum += __shfl_xor(ssum, off);
    float inv = 1.f / (ssum + eself + 1e-16f);
    w *= inv;

    int fq = lane & 7, eg = lane >> 3;
    float acc[8];
    #pragma unroll
    for (int k = 0; k < 8; k++) acc[k] = 0.f;

    if (eg == 0) {
        u16x8 hv = *(const u16x8*)(h + (size_t)wid * 64 + fq * 8);
        float en = eself * inv;
        #pragma unroll
        for (int k = 0; k < 8; k++) acc[k] = en * us2f(hv[k]);
    }
    {
        int iters = (dc + 3) >> 2;   // 1..8; it in {0,4} -> j0+12 <= 31
        for (int it = 0; it < iters; it += 4) {
            int j0 = it * 4 + eg;
            float w0 = __shfl(w, j0, 32);       int s0 = __shfl(s, j0, 32);
            float w1 = __shfl(w, j0 + 4, 32);   int s1 = __shfl(s, j0 + 4, 32);
            float w2 = __shfl(w, j0 + 8, 32);   int s2 = __shfl(s, j0 + 8, 32);
            float w3 = __shfl(w, j0 + 12, 32);  int s3 = __shfl(s, j0 + 12, 32);
            u16x8 hv0 = *(const u16x8*)(h + (size_t)s0 * 64 + fq * 8);
            u16x8 hv1 = *(const u16x8*)(h + (size_t)s1 * 64 + fq * 8);
            u16x8 hv2 = *(const u16x8*)(h + (size_t)s2 * 64 + fq * 8);
            u16x8 hv3 = *(const u16x8*)(h + (size_t)s3 * 64 + fq * 8);
            #pragma unroll
            for (int k = 0; k < 8; k++) acc[k] += w0 * us2f(hv0[k]);
            #pragma unroll
            for (int k = 0; k < 8; k++) acc[k] += w1 * us2f(hv1[k]);
            #pragma unroll
            for (int k = 0; k < 8; k++) acc[k] += w2 * us2f(hv2[k]);
            #pragma unroll
            for (int k = 0; k < 8; k++) acc[k] += w3 * us2f(hv3[k]);
        }
    }
    for (int base = 32; base < d; base += 32) {
        int cnt = min(32, d - base);
        float wx = 0.f; int sx = 0;
        if (lane < cnt) { sx = col[start + base + lane]; wx = __expf(lrelu(as_[sx] + adi)) * inv; }
        int iters = (cnt + 3) >> 2;
        for (int it = 0; it < iters; it += 2) {
            int j0 = it * 4 + eg;
            float w0 = __shfl(wx, j0, 32);      int s0 = __shfl(sx, j0, 32);
            float w1 = __shfl(wx, j0 + 4, 32);  int s1 = __shfl(sx, j0 + 4, 32);
            u16x8 hv0 = *(const u16x8*)(h + (size_t)s0 * 64 + fq * 8);
            u16x8 hv1 = *(const u16x8*)(h + (size_t)s1 * 64 + fq * 8);
            #pragma unroll
            for (int k = 0; k < 8; k++) acc[k] += w0 * us2f(hv0[k]);
            #pragma unroll
            for (int k = 0; k < 8; k++) acc[k] += w1 * us2f(hv1[k]);
        }
    }
    #pragma unroll
    for (int k = 0; k < 8; k++) {
        acc[k] += __shfl_xor(acc[k], 8);
        acc[k] += __shfl_xor(acc[k], 16);
    }
    if (lane < 8) {
        float4 b0 = ((const float4*)bias)[lane * 2];
        float4 b1 = ((const float4*)bias)[lane * 2 + 1];
        float bb[8] = {b0.x, b0.y, b0.z, b0.w, b1.x, b1.y, b1.z, b1.w};
        u16x8 ob;
        #pragma unroll
        for (int k = 0; k < 8; k++) {
            float o = acc[k] + bb[k];
            if (doElu) o = eluf(o);
            ob[k] = f2bf(o);
        }
        *(u16x8*)(out + (size_t)wid * 64 + lane * 8) = ob;
    }
}

// ---------------- Aggregation F=16 + fused BN partial stats ----------------
// 2 nodes per wave; first 32 edges fully unrolled (round-7 measured form).
// Epilogue accumulates per-block (8-node) logits sums/sumsq into a 256-slot
// scratch via 32 atomicAdds per block (12500 blocks / 256 slots ~ 49 adds per
// address) — replaces the separate k_bnstat pass over logits. Early return
// replaced by an `active` guard so the epilogue __syncthreads is uniform.

__global__ __launch_bounds__(256) void k_agg16(
    const int* __restrict__ rowptr, const int* __restrict__ deg,
    const int* __restrict__ col, const float* __restrict__ as_,
    const float* __restrict__ ad_, const unsigned short* __restrict__ h,
    const float* __restrict__ bias, float* __restrict__ out,
    float* __restrict__ bnscr, int N)
{
    __shared__ float lds_s[8][16], lds_q[8][16];
    int wid = (blockIdx.x * blockDim.x + threadIdx.x) >> 5;
    int lane = threadIdx.x & 31;
    int grp = threadIdx.x >> 5;          // 0..7
    int fq = lane & 3, eg = lane >> 2;
    float4 o = {0.f, 0.f, 0.f, 0.f};

    if (wid < N) {
        int start = rowptr[wid];
        int d = deg[wid];
        float adi = ad_[wid];
        float eself = __expf(lrelu(as_[wid] + adi));

        int dc = min(d, 32);
        float w = 0.f; int s = 0;
        if (lane < dc) { s = col[start + lane]; w = __expf(lrelu(as_[s] + adi)); }
        float ssum = w;
        for (int j = lane + 32; j < d; j += 32)
            ssum += __expf(lrelu(as_[col[start + j]] + adi));
        #pragma unroll
        for (int off = 16; off; off >>= 1) ssum += __shfl_xor(ssum, off);
        float inv = 1.f / (ssum + eself + 1e-16f);
        w *= inv;

        float4 acc = {0.f, 0.f, 0.f, 0.f};
        if (eg == 0) {
            ushort4 hv = *(const ushort4*)(h + (size_t)wid * 16 + fq * 4);
            float en = eself * inv;
            acc.x = en * us2f(hv.x); acc.y = en * us2f(hv.y);
            acc.z = en * us2f(hv.z); acc.w = en * us2f(hv.w);
        }
        {
            // dc <= 32, 8 edge-groups -> 4 quads fully unrolled, branchless
            float w0 = __shfl(w, eg, 32);       int s0 = __shfl(s, eg, 32);
            float w1 = __shfl(w, eg + 8, 32);   int s1 = __shfl(s, eg + 8, 32);
            float w2 = __shfl(w, eg + 16, 32);  int s2 = __shfl(s, eg + 16, 32);
            float w3 = __shfl(w, eg + 24, 32);  int s3 = __shfl(s, eg + 24, 32);
            ushort4 hv0 = *(const ushort4*)(h + (size_t)s0 * 16 + fq * 4);
            ushort4 hv1 = *(const ushort4*)(h + (size_t)s1 * 16 + fq * 4);
            ushort4 hv2 = *(const ushort4*)(h + (size_t)s2 * 16 + fq * 4);
            ushort4 hv3 = *(const ushort4*)(h + (size_t)s3 * 16 + fq * 4);
            acc.x += w0 * us2f(hv0.x); acc.y += w0 * us2f(hv0.y);
            acc.z += w0 * us2f(hv0.z); acc.w += w0 * us2f(hv0.w);
            acc.x += w1 * us2f(hv1.x); acc.y += w1 * us2f(hv1.y);
            acc.z += w1 * us2f(hv1.z); acc.w += w1 * us2f(hv1.w);
            acc.x += w2 * us2f(hv2.x); acc.y += w2 * us2f(hv2.y);
            acc.z += w2 * us2f(hv2.z); acc.w += w2 * us2f(hv2.w);
            acc.x += w3 * us2f(hv3.x); acc.y += w3 * us2f(hv3.y);
            acc.z += w3 * us2f(hv3.z); acc.w += w3 * us2f(hv3.w);
        }
        for (int base = 32; base < d; base += 32) {
            int cnt = min(32, d - base);
            float wy = 0.f; int sy = 0;
            if (lane < cnt) { sy = col[start + base + lane]; wy = __expf(lrelu(as_[sy] + adi)) * inv; }
            int iters = (cnt + 7) >> 3;
            for (int it = 0; it < iters; it += 2) {
                int j0 = it * 8 + eg;
                float w0 = __shfl(wy, j0, 32);      int s0 = __shfl(sy, j0, 32);
                float w1 = __shfl(wy, j0 + 8, 32);  int s1 = __shfl(sy, j0 + 8, 32);
                ushort4 hv0 = *(const ushort4*)(h + (size_t)s0 * 16 + fq * 4);
                ushort4 hv1 = *(const ushort4*)(h + (size_t)s1 * 16 + fq * 4);
                acc.x += w0 * us2f(hv0.x); acc.y += w0 * us2f(hv0.y);
                acc.z += w0 * us2f(hv0.z); acc.w += w0 * us2f(hv0.w);
                acc.x += w1 * us2f(hv1.x); acc.y += w1 * us2f(hv1.y);
                acc.z += w1 * us2f(hv1.z); acc.w += w1 * us2f(hv1.w);
            }
        }
        #pragma unroll
        for (int off = 4; off < 32; off <<= 1) {
            acc.x += __shfl_xor(acc.x, off);
            acc.y += __shfl_xor(acc.y, off);
            acc.z += __shfl_xor(acc.z, off);
            acc.w += __shfl_xor(acc.w, off);
        }
        if (lane < 4) {
            float4 b4 = ((const float4*)bias)[lane];
            o.x = acc.x + b4.x; o.y = acc.y + b4.y;
            o.z = acc.z + b4.z; o.w = acc.w + b4.w;
            ((float4*)out)[(size_t)wid * 4 + lane] = o;
        }
    }

    // BN partials: lanes 0-3 of each group hold o (zeros if inactive/other lanes)
    if (lane < 4) {
        lds_s[grp][fq * 4 + 0] = o.x; lds_q[grp][fq * 4 + 0] = o.x * o.x;
        lds_s[grp][fq * 4 + 1] = o.y; lds_q[grp][fq * 4 + 1] = o.y * o.y;
        lds_s[grp][fq * 4 + 2] = o.z; lds_q[grp][fq * 4 + 2] = o.z * o.z;
        lds_s[grp][fq * 4 + 3] = o.w; lds_q[grp][fq * 4 + 3] = o.w * o.w;
    }
    __syncthreads();
    int t = threadIdx.x;
    if (t < 32) {
        int c = t & 15, half = t >> 4;
        float v = 0.f;
        #pragma unroll
        for (int g = 0; g < 8; g++)
            v += half ? lds_q[g][c] : lds_s[g][c];
        atomicAdd(&bnscr[(blockIdx.x & 255) * 32 + half * 16 + c], v);
    }
}

// ---------------- BN reduce + apply + log_softmax + out (dtype-branched) ----------------
// Preamble reduces the 256x32 scratch to the 32 BN sums (per block; 32KB
// L2-resident reads), then the per-row normalize+log_softmax as before.

__global__ __launch_bounds__(256) void k_final(
    const float* __restrict__ logits, const float* __restrict__ bnscr,
    const float* __restrict__ gamma, const float* __restrict__ beta,
    const void* __restrict__ x1, void* __restrict__ out, int N)
{
    __shared__ float red[256];
    __shared__ float bnv[32];
    int t = threadIdx.x;
    {
        int c = t & 31, rep = t >> 5;   // 8 reps x 32 cols
        float v = 0.f;
        for (int k = rep; k < 256; k += 8) v += bnscr[k * 32 + c];
        red[t] = v;
        __syncthreads();
        if (t < 32) {
            float s = 0.f;
            #pragma unroll
            for (int r = 0; r < 8; r++) s += red[r * 32 + t];
            bnv[t] = s;
        }
        __syncthreads();
    }
    int f = detect_bf16(x1);
    int r = blockIdx.x * blockDim.x + t;
    if (r >= N) return;
    float invN = 1.f / (float)N;
    float y[16];
    float mx = -1e30f;
    #pragma unroll
    for (int c = 0; c < 16; c++) {
        float mu = bnv[c] * invN;
        float var = bnv[16 + c] * invN - mu * mu;
        float v = (logits[r * 16 + c] - mu) * rsqrtf(var + 1e-5f);
        v = v * gamma[c] + beta[c];
        y[c] = v;
        mx = fmaxf(mx, v);
    }
    float se = 0.f;
    #pragma unroll
    for (int c = 0; c < 16; c++) se += __expf(y[c] - mx);
    float lse = mx + __logf(se);
    #pragma unroll
    for (int c = 0; c < 16; c++) {
        float v = y[c] - lse;
        if (f) ((__hip_bfloat16*)out)[r * 16 + c] = __float2bfloat16(v);
        else   ((float*)out)[r * 16 + c] = v;
    }
}

// ---------------- launch ----------------

extern "C" void kernel_launch(void* const* d_in, const int* in_sizes, int n_in,
                              void* d_out, int out_size, void* d_ws, size_t ws_size,
                              hipStream_t stream) {
    const void* x1  = d_in[0];
    const void* x2  = d_in[1];
    const int*  ei1 = (const int*)d_in[2];
    const int*  ei2 = (const int*)d_in[3];

    const int N = in_sizes[0] / 64;
    const int E = in_sizes[2] / 2;
    const int nb = (N + BK - 1) >> SH;   // 512-node buckets
    const int NB = 2 * nb;
    const int chunk = (2 * E + NBLK - 1) / NBLK;

    char* p = (char*)d_ws;
    auto alloc = [&](size_t bytes) {
        void* q = (void*)p;
        p += (bytes + 255) & ~(size_t)255;
        return q;
    };
    float* bnscr    = (float*)alloc(256 * 32 * 4);          // zeroed by memset
    unsigned short* h0 = (unsigned short*)alloc((size_t)N * 64 * 2);  // bf16
    unsigned short* h1 = (unsigned short*)alloc((size_t)N * 64 * 2);  // bf16
    unsigned short* hlin = (unsigned short*)alloc((size_t)N * 64 * 2);  // bf16
    float* as_      = (float*)alloc((size_t)N * 4);
    float* ad_      = (float*)alloc((size_t)N * 4);
    int* rowptr1    = (int*)alloc((size_t)N * 4);
    int* deg1       = (int*)alloc((size_t)N * 4);
    int* rowptr2    = (int*)alloc((size_t)N * 4);
    int* deg2       = (int*)alloc((size_t)N * 4);
    int* col1       = (int*)alloc((size_t)nb * CAPB * 4);   // aliased as logits later
    int* col2       = (int*)alloc((size_t)nb * CAPB * 4);
    int* counts     = (int*)alloc((size_t)NB * NBLK * 4);
    int* bfill      = (int*)alloc((size_t)NB * 4);
    float* P        = (float*)alloc(P_TOTAL * 4);
    float* logits   = (float*)col1;  // col1 dead after layer-0 agg

    // bedge (packed uint, NB*CAPB*4 = ~19.3MB) aliases h0/h1 head (25.6MB).
    // Safe: bedge fully consumed by k_bucket2 before any h0/h1 write; front's
    // gemm0 writes only hlin/as_/ad_ which do NOT overlap bedge.
    unsigned int* bedge   = (unsigned int*)h0;
    unsigned int* bedge2p = bedge + (size_t)nb * CAPB;

    hipMemsetAsync(bnscr, 0, 256 * 32 * 4, stream);

    const int TB = 256;
    int gN = (N + TB - 1) / TB;
    int gW = (N + 7) / 8;       // 2 nodes per wave, 8 nodes per 256-thr block
    int nt = (N + 63) / 64;
    int gT = nt < 1024 ? nt : 1024;   // short streaming blocks, 1-2 tiles each

    Ptrs6 pp;
    pp.p[0] = d_in[7];   // b0
    pp.p[1] = d_in[11];  // b1
    pp.p[2] = d_in[15];  // b2
    pp.p[3] = d_in[16];  // gamma
    pp.p[4] = d_in[17];  // beta
    pp.p[5] = x1;        // dtype probe

    // Front: CSR count || layer-0 GEMM || params (independent; count first)
    k_front<<<NBLK + gT + 1, TB, 0, stream>>>(
        x1, ei1, ei2, E, counts, nb, NB, chunk,
        d_in[4], d_in[5], d_in[6], hlin, as_, ad_, N, nt, gT, pp, P);

    // CSR: scan -> place (LDS-reordered) -> per-bucket node sort
    k_scan<<<NB, TB, 0, stream>>>(counts, bfill);
    k_place<<<NBLK, TB, 0, stream>>>(ei1, ei2, E, counts, bedge, nb, NB, chunk);
    k_bucket2<<<NB, TB, 0, stream>>>(bfill, bedge, rowptr1, deg1, col1,
                                     bfill + nb, bedge2p, rowptr2, deg2, col2, nb, N);

    // Layer 0 aggregate: graph1 -> h0 (elu, bf16)
    k_agg64<<<gW, TB, 0, stream>>>(rowptr1, deg1, col1, as_, ad_, hlin, P + P_B0, h0, N, 1);

    // Layer 1: [h0 bf16 | x2 raw] @ W1 -> hlin (bf16); aggregate graph2 -> h1
    k_gemm<128, 64><<<gT, TB, 0, stream>>>(
        h0, 0, x2, 1, d_in[8], d_in[9], d_in[10], hlin, as_, ad_, N, nt, gT);
    k_agg64<<<gW, TB, 0, stream>>>(rowptr2, deg2, col2, as_, ad_, hlin, P + P_B1, h1, N, 1);

    // Layer 2: [h0 | h1] @ W2 -> hlin(:,:16); aggregate graph2 -> logits + BN partials
    k_gemm<128, 16><<<gT, TB, 0, stream>>>(
        h0, 0, h1, 0, d_in[12], d_in[13], d_in[14], hlin, as_, ad_, N, nt, gT);
    k_agg16<<<gW, TB, 0, stream>>>(rowptr2, deg2, col2, as_, ad_, hlin, P + P_B2,
                                   logits, bnscr, N);

    // BN reduce + log_softmax (k_bnstat fused into agg16 epilogue)
    k_final<<<gN, TB, 0, stream>>>(logits, bnscr, P + P_GAMMA, P + P_BETA, x1, d_out, N);
}